// Round 18
// baseline (2541.312 us; speedup 1.0000x reference)
//
#include <hip/hip_runtime.h>

typedef float v2f __attribute__((ext_vector_type(2)));
typedef unsigned uv2 __attribute__((ext_vector_type(2)));

constexpr int NX = 32, NU = 16, NF = 512;
constexpr int SEQ = 2048;
constexpr int NT = 256;           // 4 waves/block; 2 rows/block; 2 features/thread
constexpr float SC  = 2.88539008177792681f;  // 2/ln2: tanh(a) = 1 - 2/(exp2(SC*a)+1)
constexpr float TSC = 0.01f;

// DPP partner read (VALU pipe). Direction-proof controls only:
// 0xB1 quad_perm xor1 | 0x4E quad_perm xor2 | 0x128 row_ror:8 (= xor8 both directions)
template<int CTRL>
__device__ __forceinline__ float dpp_mov(float v) {
    return __int_as_float(__builtin_amdgcn_update_dpp(0, __float_as_int(v), CTRL, 0xF, 0xF, true));
}
// gfx950 permlane swaps (VALU pipe): v[l] + v[l^16] / v[l^32]
__device__ __forceinline__ float sum16(float v) {
    uv2 r = __builtin_amdgcn_permlane16_swap(__float_as_uint(v), __float_as_uint(v), false, false);
    return __uint_as_float(r.x) + __uint_as_float(r.y);
}
__device__ __forceinline__ float sum32(float v) {
    uv2 r = __builtin_amdgcn_permlane32_swap(__float_as_uint(v), __float_as_uint(v), false, false);
    return __uint_as_float(r.x) + __uint_as_float(r.y);
}

__device__ __forceinline__ float tanh4(float y) {       // y pre-scaled by SC
    const float e = __builtin_amdgcn_exp2f(y);
    const float r = __builtin_amdgcn_rcpf(e + 1.f);
    return fmaf(-2.f, r, 1.f);
}

// LDS barrier: orders memory ops only; register-only VALU may cross.
__device__ __forceinline__ void bar_lds() {
    asm volatile("s_waitcnt lgkmcnt(0)" ::: "memory");
    __builtin_amdgcn_s_barrier();
    asm volatile("" ::: "memory");
}

__global__ __launch_bounds__(NT)
__attribute__((amdgpu_waves_per_eu(1, 1)))   // 4 waves/CU total -> full 512-reg budget/wave
void fes_kernel(const float* __restrict__ x0, const float* __restrict__ ug,
                const float* __restrict__ W1, const float* __restrict__ b1,
                const float* __restrict__ W2, const float* __restrict__ b2,
                float* __restrict__ out)
{
    __shared__ __align__(16) float xs_w[4][2][NX];  // per-wave, per-row state copies
    __shared__ float part[2][2][8][33];             // [buf][row][slot][j], stride 33: conflict-free

    const int tid = threadIdx.x;
    const int rowA = 2 * blockIdx.x, rowB = rowA + 1;
    const int l = tid & 63, w = tid >> 6;

    // lane -> owned output j (XOR-linear): pi(1)=16, pi(2)=8, pi(8)=4, pi(16)=2, pi(32)=1, pi(4)=0
    const int pi = ((l & 1) << 4) | (((l >> 1) & 1) << 3) | (((l >> 3) & 1) << 2)
                 | (((l >> 4) & 1) << 1) | ((l >> 5) & 1);
    const int slot = 2 * w + ((l >> 2) & 1);        // 8 coset-partials per j per row
    const bool jown = (l & 4) == 0;

    const int f0 = 2 * tid, f1 = f0 + 1;            // this thread's two features (shared by both rows)

    // ---- persistent weights (shared across rows) -------------------------
    v2f wkA[24], wkB[24];                           // G1 weights, k-parity pairs (k=0..47)
#pragma unroll
    for (int p = 0; p < 24; ++p) {
        wkA[p] = v2f{SC * W1[(2 * p) * NF + f0], SC * W1[(2 * p + 1) * NF + f0]};
        wkB[p] = v2f{SC * W1[(2 * p) * NF + f1], SC * W1[(2 * p + 1) * NF + f1]};
    }
    const float b1A = SC * b1[f0], b1B = SC * b1[f1];

    v2f wcA[16], wcB[16];                           // G2 weights, pi-domain
#pragma unroll
    for (int m = 0; m < 16; ++m) {
        wcA[m] = v2f{TSC * W2[f0 * NX + ((2 * m) ^ pi)], TSC * W2[f0 * NX + ((2 * m + 1) ^ pi)]};
        wcB[m] = v2f{TSC * W2[f1 * NX + ((2 * m) ^ pi)], TSC * W2[f1 * NX + ((2 * m + 1) ^ pi)]};
    }
    const float bb = TSC * b2[pi];

    float xrA = x0[rowA * NX + pi];
    float xrB = x0[rowB * NX + pi];

    const float* ugA  = ug  + (size_t)rowA * SEQ * NU;
    const float* ugB  = ug  + (size_t)rowB * SEQ * NU;
    float*       outA = out + (size_t)rowA * SEQ * NX;
    float*       outB = out + (size_t)rowB * SEQ * NX;

    if (jown) {
        xs_w[w][0][pi] = xrA;                       // wave-private: in-wave ordering suffices
        xs_w[w][1][pi] = xrB;
    }
    const float4* xsA = (const float4*)xs_w[w][0];
    const float4* xsB = (const float4*)xs_w[w][1];

    float4 uA0 = *(const float4*)(ugA + 0), uA1 = *(const float4*)(ugA + 4);
    float4 uA2 = *(const float4*)(ugA + 8), uA3 = *(const float4*)(ugA + 12);
    float4 uB0 = *(const float4*)(ugB + 0), uB1 = *(const float4*)(ugB + 4);
    float4 uB2 = *(const float4*)(ugB + 8), uB3 = *(const float4*)(ugB + 12);

#pragma unroll 1
    for (int t = 0; t < SEQ; ++t) {
        // ================= row A: G1 =================
        v2f pA0 = {b1A, 0.f}, pA1 = {0.f, 0.f};     // feature f0 acc
        v2f qA0 = {b1B, 0.f}, qA1 = {0.f, 0.f};     // feature f1 acc
#pragma unroll
        for (int s = 0; s < 8; ++s) {
            const float4 iv = xsA[s];               // wave-uniform broadcast
            const v2f lo = {iv.x, iv.y}, hi = {iv.z, iv.w};
            pA0 += wkA[2 * s] * lo;  pA1 += wkA[2 * s + 1] * hi;
            qA0 += wkB[2 * s] * lo;  qA1 += wkB[2 * s + 1] * hi;
        }
#define UPART(uv, p0, pe, po, qe, qo)                                       \
        { const v2f lo = {uv.x, uv.y}, hi = {uv.z, uv.w};                   \
          pe += wkA[p0] * lo;  po += wkA[p0 + 1] * hi;                      \
          qe += wkB[p0] * lo;  qo += wkB[p0 + 1] * hi; }
        UPART(uA0, 16, pA0, pA1, qA0, qA1)
        UPART(uA1, 18, pA0, pA1, qA0, qA1)
        UPART(uA2, 20, pA0, pA1, qA0, qA1)
        UPART(uA3, 22, pA0, pA1, qA0, qA1)
        const float h0A = tanh4((pA0.x + pA0.y) + (pA1.x + pA1.y));
        const float h1A = tanh4((qA0.x + qA0.y) + (qA1.x + qA1.y));

        // ================= row B: G1 =================
        v2f pB0 = {b1A, 0.f}, pB1 = {0.f, 0.f};
        v2f qB0 = {b1B, 0.f}, qB1 = {0.f, 0.f};
#pragma unroll
        for (int s = 0; s < 8; ++s) {
            const float4 iv = xsB[s];
            const v2f lo = {iv.x, iv.y}, hi = {iv.z, iv.w};
            pB0 += wkA[2 * s] * lo;  pB1 += wkA[2 * s + 1] * hi;
            qB0 += wkB[2 * s] * lo;  qB1 += wkB[2 * s + 1] * hi;
        }
        UPART(uB0, 16, pB0, pB1, qB0, qB1)
        UPART(uB1, 18, pB0, pB1, qB0, qB1)
        UPART(uB2, 20, pB0, pB1, qB0, qB1)
        UPART(uB3, 22, pB0, pB1, qB0, qB1)
#undef UPART
        const float h0B = tanh4((pB0.x + pB0.y) + (pB1.x + pB1.y));
        const float h1B = tanh4((qB0.x + qB0.y) + (qB1.x + qB1.y));

        // ================= G2 + reduce-scatter, row A =================
        float SA;
        {
            const v2f h0v = {h0A, h0A}, h1v = {h1A, h1A};
            v2f r[16];
#pragma unroll
            for (int m = 0; m < 16; ++m) r[m] = h0v * wcA[m] + h1v * wcB[m];
#pragma unroll
            for (int m = 0; m < 8; ++m) {             // d=1 (j-bit 16)
                r[m].x += dpp_mov<0xB1>(r[m + 8].x);
                r[m].y += dpp_mov<0xB1>(r[m + 8].y);
            }
#pragma unroll
            for (int m = 0; m < 4; ++m) {             // d=2 (j-bit 8)
                r[m].x += dpp_mov<0x4E>(r[m + 4].x);
                r[m].y += dpp_mov<0x4E>(r[m + 4].y);
            }
#pragma unroll
            for (int m = 0; m < 2; ++m) {             // d=8 (j-bit 4)
                r[m].x += dpp_mov<0x128>(r[m + 2].x);
                r[m].y += dpp_mov<0x128>(r[m + 2].y);
            }
            const float S0 = r[0].x + (sum16(r[1].x) - r[1].x);   // d=16
            const float S1 = r[0].y + (sum16(r[1].y) - r[1].y);
            SA = S0 + (sum32(S1) - S1);                           // d=32
        }
        part[t & 1][0][slot][pi] = SA;

        // ================= G2 + reduce-scatter, row B =================
        float SB;
        {
            const v2f h0v = {h0B, h0B}, h1v = {h1B, h1B};
            v2f r[16];
#pragma unroll
            for (int m = 0; m < 16; ++m) r[m] = h0v * wcA[m] + h1v * wcB[m];
#pragma unroll
            for (int m = 0; m < 8; ++m) {
                r[m].x += dpp_mov<0xB1>(r[m + 8].x);
                r[m].y += dpp_mov<0xB1>(r[m + 8].y);
            }
#pragma unroll
            for (int m = 0; m < 4; ++m) {
                r[m].x += dpp_mov<0x4E>(r[m + 4].x);
                r[m].y += dpp_mov<0x4E>(r[m + 4].y);
            }
#pragma unroll
            for (int m = 0; m < 2; ++m) {
                r[m].x += dpp_mov<0x128>(r[m + 2].x);
                r[m].y += dpp_mov<0x128>(r[m + 2].y);
            }
            const float S0 = r[0].x + (sum16(r[1].x) - r[1].x);
            const float S1 = r[0].y + (sum16(r[1].y) - r[1].y);
            SB = S0 + (sum32(S1) - S1);
        }
        part[t & 1][1][slot][pi] = SB;

        // ---- prefetch u(t+1) for both rows (no vmcnt drain at barrier) ---
        {
            const int tn = (t + 1 < SEQ) ? t + 1 : SEQ - 1;
            const float* unA = ugA + (size_t)tn * NU;
            const float* unB = ugB + (size_t)tn * NU;
            uA0 = *(const float4*)(unA + 0);  uA1 = *(const float4*)(unA + 4);
            uA2 = *(const float4*)(unA + 8);  uA3 = *(const float4*)(unA + 12);
            uB0 = *(const float4*)(unB + 0);  uB1 = *(const float4*)(unB + 4);
            uB2 = *(const float4*)(unB + 8);  uB3 = *(const float4*)(unB + 12);
        }

        bar_lds();

        // ---- combine both rows: 16 b32 reads (stride 33, conflict-free) --
        const float* pa = &part[t & 1][0][0][pi];
        const float a0 = pa[0],   a1 = pa[33],  a2 = pa[66],  a3 = pa[99];
        const float a4 = pa[132], a5 = pa[165], a6 = pa[198], a7 = pa[231];
        const float* pbq = &part[t & 1][1][0][pi];
        const float c0 = pbq[0],   c1 = pbq[33],  c2 = pbq[66],  c3 = pbq[99];
        const float c4 = pbq[132], c5 = pbq[165], c6 = pbq[198], c7 = pbq[231];
        const float xnA = xrA + ((((a0 + a1) + (a2 + a3)) + ((a4 + a5) + (a6 + a7))) + bb);
        const float xnB = xrB + ((((c0 + c1) + (c2 + c3)) + ((c4 + c5) + (c6 + c7))) + bb);
        xrA = xnA; xrB = xnB;

        if (w == 0 && jown) outA[(size_t)t * NX + pi] = xnA;   // stores split across waves
        if (w == 1 && jown) outB[(size_t)t * NX + pi] = xnB;
        if (jown) {
            xs_w[w][0][pi] = xnA;               // own wave's copies (lgkm-ordered)
            xs_w[w][1][pi] = xnB;
        }
    }
}

extern "C" void kernel_launch(void* const* d_in, const int* in_sizes, int n_in,
                              void* d_out, int out_size, void* d_ws, size_t ws_size,
                              hipStream_t stream) {
    const float* x0 = (const float*)d_in[0];
    const float* ug = (const float*)d_in[1];
    const float* W1 = (const float*)d_in[2];
    const float* b1 = (const float*)d_in[3];
    const float* W2 = (const float*)d_in[4];
    const float* b2 = (const float*)d_in[5];
    float* out = (float*)d_out;

    fes_kernel<<<dim3(256), dim3(NT), 0, stream>>>(x0, ug, W1, b1, W2, b2, out);
}